// Round 3
// baseline (221.840 us; speedup 1.0000x reference)
//
#include <hip/hip_runtime.h>
#include <stdint.h>

// AudioSNN: conv1(1->32)+spike+pool -> conv2(32->64)+spike+pool -> fc1
// -> 25-step LIF (fc2, fc3).
// conv2, fc1, fc2/fc3 all run on MFMA: activations/spikes are exact small
// integers (exact fp16), weights use an exact 2-way fp16 split (err ~2^-22).
// R9: conv2 = persistent per-sample block with 2-deep pipeline. R2 profile:
// MfmaUtil 30%, VALUBusy 20%, Occ 32%, WRITE_SIZE 25.9MB for 8MB payload
// (partial-line RMW: h=0/h=1 blocks each wrote 64B halves of 128B lines).
// Changes:
//   - one block per sample, double-buffered cin: h=1 global loads issued
//     BEFORE the h=0 MFMA region (HBM latency hides under 1152 MFMAs),
//     unpacked into buf1 after the h=0 epilogue. Removes one serial stage
//     stall per block and decouples from cross-block phase alignment.
//   - both halves' counts staged in LDS cnt[64][144pad]; xq written once as
//     full 128B lines -> kills the RMW write amplification.
//   - k_prep merged into k_conv1 (disjoint I/O; mem-bound prep overlaps
//     VALU-bound conv1; one launch gap removed).
// Per-accumulator MFMA chain order (taps row-major, hi then lo) identical
// to R1/R2 -> bit-identical spike decisions. fc1/lif unchanged.
//
// ws layout:
//   part f32 [32][1024][256]       @0     32 MB   (c1q u8 [1024][512][32]
//                                                  aliases the first 16.8 MB
//                                                  during the conv stage)
//   xq   u8  [1024][8192]          @32M    8 MB
//   afrag f16 [9][4][2][512]       @41M   72 KB  (conv2 A fragments hi/lo)
//   w1s  f16 [2][16][256][512]     @42M    8 MB  (fc1 A fragments hi/lo planes)

#define NSTEP 25

using half8   = __attribute__((ext_vector_type(8))) _Float16;
using half4v  = __attribute__((ext_vector_type(4))) _Float16;
using float4v = __attribute__((ext_vector_type(4))) float;

__device__ __forceinline__ float lif_update(float mem, float cur) {
#pragma clang fp contract(off)
  float reset = (mem > 1.0f) ? 1.0f : 0.0f;
  float m = 0.95f * mem;
  m = m + cur;
  m = m - reset;
  return m;
}

// --------------------------------------- merged conv1 + weight prep
// blocks 0..1023: conv1 (pure VALU, one sample each)
// blocks 1024..1095: conv2 afrag prep (9 taps x 4 mtiles x 2 splits)
// blocks 1096..2119: fc1 w1s prep (4 fragment-groups per block)
__global__ __launch_bounds__(256, 4) void k_pc1(const float* __restrict__ x,
                                                const float* __restrict__ w1c,
                                                const float* __restrict__ b1c,
                                                uint8_t* __restrict__ c1q,
                                                const float* __restrict__ w2c,
                                                const float* __restrict__ w1,
                                                _Float16* __restrict__ afrag,
                                                _Float16* __restrict__ w1s) {
  __shared__ float xin[66 * 34];          // conv1 input + halo
  __shared__ float wl[288];
  __shared__ float bl[32];
  const int t = threadIdx.x;
  const int b = blockIdx.x;

  if (b >= 1024) {                        // ---- prep paths
    const int bp = b - 1024;
    if (bp < 72) {
      if (t < 64) {
        const int tp = bp >> 3;
        const int mt = (bp & 7) >> 1;
        const int sp = bp & 1;
        const int m = t & 15, quad = t >> 4;
#pragma unroll
        for (int j = 0; j < 8; ++j) {
          int ch = quad * 8 + j;
          int oc = mt * 16 + m;
          float wv = w2c[(size_t)(oc * 32 + ch) * 9 + tp];
          float hi = (float)(_Float16)wv;
          _Float16 val = (sp == 0) ? (_Float16)wv : (_Float16)(wv - hi);
          afrag[(size_t)bp * 512 + t * 8 + j] = val;
        }
      }
      return;
    }
    const int W = (bp - 72) * 4 + (t >> 6);  // 0..4095 = mt*256+kcg
    const int lane = t & 63;
    const int mt = W >> 8, kcg = W & 255;
    const int m = lane & 15, quad = lane >> 4;
    const float* src = w1 + (size_t)(mt * 16 + m) * 8192 + kcg * 32 + quad * 8;
    float4 u0 = *(const float4*)src;
    float4 u1 = *(const float4*)(src + 4);
    float wv[8] = {u0.x, u0.y, u0.z, u0.w, u1.x, u1.y, u1.z, u1.w};
    half8 hi, lo;
#pragma unroll
    for (int e = 0; e < 8; ++e) {
      float h = (float)(_Float16)wv[e];
      hi[e] = (_Float16)wv[e];
      lo[e] = (_Float16)(wv[e] - h);
    }
    _Float16* dst = w1s + ((size_t)W) * 512 + lane * 8;
    *(half8*)dst = hi;
    *(half8*)(dst + (size_t)16 * 256 * 512) = lo;   // lo plane at +4 MB
    return;
  }

  // ---- conv1 path (pure VALU, one sample)
  const int s = b;
  for (int idx = t; idx < 66 * 34; idx += 256) xin[idx] = 0.0f;
  wl[t] = w1c[t];
  if (t < 32) { wl[256 + t] = w1c[256 + t]; bl[t] = b1c[t]; }
  __syncthreads();

  const float* xs = x + (size_t)s * (64 * 32);
#pragma unroll
  for (int r = 0; r < 2; ++r) {
    int idx = t + r * 256;
    int y = idx >> 3, q = idx & 7;
    float4 v = *(const float4*)(xs + y * 32 + q * 4);
    float* dst = &xin[(y + 1) * 34 + q * 4 + 1];
    dst[0] = v.x; dst[1] = v.y; dst[2] = v.z; dst[3] = v.w;
  }
  __syncthreads();

  const int ch = t & 31;
  const int po = t >> 5;
  float wc[9];
#pragma unroll
  for (int i = 0; i < 9; ++i) wc[i] = wl[ch * 9 + i];
  const float bv = bl[ch];
  uint8_t* cs = c1q + (size_t)s * 16384;
  for (int rr = 0; rr < 64; ++rr) {
    int pos = rr * 8 + po;
    int py = pos >> 4, px = pos & 15;
    float p[4][4];
#pragma unroll
    for (int rw = 0; rw < 4; ++rw) {
      float2 a = *(const float2*)&xin[(2 * py + rw) * 34 + 2 * px];
      float2 bq = *(const float2*)&xin[(2 * py + rw) * 34 + 2 * px + 2];
      p[rw][0] = a.x; p[rw][1] = a.y; p[rw][2] = bq.x; p[rw][3] = bq.y;
    }
    int cnt = 0;
#pragma unroll
    for (int dy = 0; dy < 2; ++dy)
#pragma unroll
      for (int dx = 0; dx < 2; ++dx) {
        float acc = 0.0f;
#pragma unroll
        for (int ky = 0; ky < 3; ++ky)
#pragma unroll
          for (int kx = 0; kx < 3; ++kx)
            acc += wc[ky * 3 + kx] * p[dy + ky][dx + kx];
        float v = acc + bv;
        cnt += (v > 1.0f) ? 1 : 0;
      }
    cs[pos * 32 + ch] = (uint8_t)cnt;
  }
}

// -------------------------------------------- conv2 (persistent per-sample)
// Implicit GEMM per half: M=64 oc, N=256 pos, K=32 ch x 9 taps, hi/lo split.
// 256 thr = 4 waves; wave w owns pre-pool local rows w*4..w*4+3 (acc[4][4]).
// 2-deep pipeline: h=1 loads issued before the h=0 MFMA region.
// LDS: 2 x 25.9 KB cin + 9 KB cnt -> 2 blocks/CU; grid 1024 = 2 rounds.

#define UNPACK(BUF, U0, U1, LR, PXL)                                        \
  {                                                                         \
    uint32_t wd[8] = {U0.x, U0.y, U0.z, U0.w, U1.x, U1.y, U1.z, U1.w};      \
    _Float16* dst = &BUF[((LR) * 18 + (PXL) + 1) * 40];                     \
    _Pragma("unroll")                                                       \
    for (int g = 0; g < 4; ++g) {                                           \
      half8 hv;                                                             \
      _Pragma("unroll")                                                     \
      for (int e = 0; e < 8; ++e) {                                         \
        uint32_t word = wd[g * 2 + (e >> 2)];                               \
        hv[e] = (_Float16)(unsigned short)((word >> ((e & 3) * 8)) & 0xffu);\
      }                                                                     \
      *(half8*)(dst + g * 8) = hv;                                          \
    }                                                                       \
  }

#define CONV2_MFMA(BUF, ACC)                                                \
  _Pragma("unroll")                                                         \
  for (int ky = 0; ky < 3; ++ky)                                            \
    _Pragma("unroll")                                                       \
    for (int kx = 0; kx < 3; ++kx) {                                        \
      const int tp = ky * 3 + kx;                                           \
      half8 bfr[4];                                                         \
      _Pragma("unroll")                                                     \
      for (int nt = 0; nt < 4; ++nt) {                                      \
        int row = wave * 4 + nt + ky;                                       \
        int col = xlane + kx;                                               \
        bfr[nt] = *(const half8*)&BUF[(row * 18 + col) * 40 + quad * 8];    \
      }                                                                     \
      _Pragma("unroll")                                                     \
      for (int mt = 0; mt < 4; ++mt) {                                      \
        half8 ah = *(const half8*)(afrag +                                  \
                     ((size_t)((tp * 4 + mt) * 2 + 0)) * 512 + lane * 8);   \
        half8 al = *(const half8*)(afrag +                                  \
                     ((size_t)((tp * 4 + mt) * 2 + 1)) * 512 + lane * 8);   \
        _Pragma("unroll")                                                   \
        for (int nt = 0; nt < 4; ++nt) {                                    \
          ACC[mt][nt] = __builtin_amdgcn_mfma_f32_16x16x32_f16(ah, bfr[nt], \
                                                        ACC[mt][nt], 0,0,0);\
          ACC[mt][nt] = __builtin_amdgcn_mfma_f32_16x16x32_f16(al, bfr[nt], \
                                                        ACC[mt][nt], 0,0,0);\
        }                                                                   \
      }                                                                     \
    }

#define CONV2_EPI(ACC, H)                                                   \
  _Pragma("unroll")                                                         \
  for (int mt = 0; mt < 4; ++mt)                                            \
    _Pragma("unroll")                                                       \
    for (int ntp = 0; ntp < 2; ++ntp) {                                     \
      int py = wave * 2 + ntp;                                              \
      _Pragma("unroll")                                                     \
      for (int r = 0; r < 4; ++r) {                                         \
        float v0 = 0.25f * ACC[mt][2 * ntp + 0][r] + bw[mt][r];             \
        float v1 = 0.25f * ACC[mt][2 * ntp + 1][r] + bw[mt][r];             \
        int c = ((v0 > 1.0f) ? 1 : 0) + ((v1 > 1.0f) ? 1 : 0);              \
        c += __shfl_xor(c, 1, 64);                                          \
        if (writer) {                                                       \
          int oc = mt * 16 + quad * 4 + r;                                  \
          cnt[oc * 144 + (H) * 64 + py * 8 + px] = (uint8_t)c;              \
        }                                                                   \
      }                                                                     \
    }

__global__ __launch_bounds__(256, 2) void k_conv2(const uint8_t* __restrict__ c1q,
                                                  const _Float16* __restrict__ afrag,
                                                  const float* __restrict__ b2c,
                                                  uint8_t* __restrict__ xq) {
  __shared__ _Float16 cin0[18 * 18 * 40];   // 25920 B each
  __shared__ _Float16 cin1[18 * 18 * 40];
  __shared__ uint8_t cnt[64 * 144];         // [oc][128 + pad16] 9216 B
  const int t = threadIdx.x;
  const int s = blockIdx.x;
  const uint8_t* base = c1q + (size_t)s * 16384;

  // ---- issue h=0 loads (rows gr = -1 + lr)
  uint4 a0, a1, a2, a3;
  bool va = false, vb = false;
  {
    const int lr = t >> 4, pxl = t & 15, gr = lr - 1;
    if (gr >= 0) {
      const uint8_t* p = base + (size_t)(gr * 16 + pxl) * 32;
      a0 = *(const uint4*)p; a1 = *(const uint4*)(p + 16); va = true;
    }
  }
  if (t < 32) {
    const int lr = 16 + (t >> 4), pxl = t & 15, gr = lr - 1;  // gr 15,16
    const uint8_t* p = base + (size_t)(gr * 16 + pxl) * 32;
    a2 = *(const uint4*)p; a3 = *(const uint4*)(p + 16); vb = true;
  }

  {  // zero both buffers (covers halo rows/cols and ch pad)
    half8* c0 = (half8*)cin0;
    half8* c1 = (half8*)cin1;
    half8 z = {};
    for (int idx = t; idx < 1620; idx += 256) { c0[idx] = z; c1[idx] = z; }
  }
  __syncthreads();

  // ---- unpack h=0 into cin0
  if (va) { const int lr = t >> 4, pxl = t & 15; UNPACK(cin0, a0, a1, lr, pxl); }
  if (vb) { const int lr = 16 + (t >> 4), pxl = t & 15; UNPACK(cin0, a2, a3, lr, pxl); }

  // ---- issue h=1 loads (rows gr = 15 + lr) — latency hides under MFMA(h=0)
  uint4 c0v, c1v, c2v, c3v;
  bool vc = false;
  {
    const int lr = t >> 4, pxl = t & 15, gr = 15 + lr;  // gr 15..30, valid
    const uint8_t* p = base + (size_t)(gr * 16 + pxl) * 32;
    c0v = *(const uint4*)p; c1v = *(const uint4*)(p + 16);
  }
  if (t < 16) {  // lr 16 -> gr 31 valid; lr 17 -> gr 32 halo (stays zero)
    const int pxl = t & 15;
    const uint8_t* p = base + (size_t)(31 * 16 + pxl) * 32;
    c2v = *(const uint4*)p; c3v = *(const uint4*)(p + 16); vc = true;
  }
  __syncthreads();   // cin0 ready

  const int lane = t & 63;
  const int wave = __builtin_amdgcn_readfirstlane(t >> 6);  // 0..3
  const int xlane = lane & 15, quad = lane >> 4;
  const int px = xlane >> 1;
  const bool writer = (xlane & 1) == 0;

  float bw[4][4];
#pragma unroll
  for (int mt = 0; mt < 4; ++mt)
#pragma unroll
    for (int r = 0; r < 4; ++r) bw[mt][r] = b2c[mt * 16 + quad * 4 + r];

  {  // ---- half 0: MFMA + epilogue
    float4v acc[4][4];
#pragma unroll
    for (int mt = 0; mt < 4; ++mt)
#pragma unroll
      for (int nt = 0; nt < 4; ++nt) acc[mt][nt] = (float4v){0.f, 0.f, 0.f, 0.f};
    CONV2_MFMA(cin0, acc)
    CONV2_EPI(acc, 0)
  }

  // ---- unpack h=1 into cin1 (disjoint from cin0 -> no barrier needed first)
  { const int lr = t >> 4, pxl = t & 15; UNPACK(cin1, c0v, c1v, lr, pxl); }
  if (vc) { const int pxl = t & 15; UNPACK(cin1, c2v, c3v, 16, pxl); }
  __syncthreads();   // cin1 ready (and h0 cnt writes done)

  {  // ---- half 1: MFMA + epilogue
    float4v acc[4][4];
#pragma unroll
    for (int mt = 0; mt < 4; ++mt)
#pragma unroll
      for (int nt = 0; nt < 4; ++nt) acc[mt][nt] = (float4v){0.f, 0.f, 0.f, 0.f};
    CONV2_MFMA(cin1, acc)
    CONV2_EPI(acc, 1)
  }
  __syncthreads();   // cnt complete

  // ---- coalesced full-line write-out: thread t -> oc = t>>2, seg = t&3
  {
    const int oc = t >> 2, seg = t & 3;
    const uint8_t* sp = &cnt[oc * 144 + seg * 32];
    uint4 v0 = *(const uint4*)sp;
    uint4 v1 = *(const uint4*)(sp + 16);
    uint8_t* dp = xq + (size_t)s * 8192 + oc * 128 + seg * 32;
    *(uint4*)dp = v0;
    *(uint4*)(dp + 16) = v1;
  }
}

// ---------------------------------------------------------------- fc1 (MFMA)
__global__ __launch_bounds__(256, 2) void k_fc1(const uint8_t* __restrict__ xq,
                                                const _Float16* __restrict__ w1s,
                                                float* __restrict__ part) {
  __shared__ _Float16 bt[8 * 4 * 64 * 8];   // [kc][nt][lane][8] = 32 KB
  const int t = threadIdx.x;
  const int sblk = blockIdx.x >> 5;   // 16 sample tiles of 64
  const int kblk = blockIdx.x & 31;   // 32 K slices of 256
  const int sb = sblk * 64;

  {  // stage B: u8 counts -> fp16, frag-ready
    const int row = t >> 2;
    const int seg = t & 3;
    const int nt = row >> 4, n16 = row & 15;
    const uint8_t* src = xq + (size_t)(sb + row) * 8192 + kblk * 256 + seg * 64;
#pragma unroll
    for (int q = 0; q < 4; ++q) {
      uint4 u = *(const uint4*)(src + q * 16);
      uint32_t wd[4] = {u.x, u.y, u.z, u.w};
#pragma unroll
      for (int g = 0; g < 2; ++g) {
        half8 h;
#pragma unroll
        for (int e = 0; e < 8; ++e) {
          uint32_t word = wd[g * 2 + (e >> 2)];
          h[e] = (_Float16)(unsigned short)((word >> ((e & 3) * 8)) & 0xffu);
        }
        int koff = seg * 64 + q * 16 + g * 8;
        int kc = koff >> 5, quad = (koff >> 3) & 3;
        *(half8*)&bt[(((kc * 4 + nt) * 64) + quad * 16 + n16) * 8] = h;
      }
    }
  }
  __syncthreads();

  const int lane = t & 63;
  const int wave = __builtin_amdgcn_readfirstlane(t >> 6);

  float4v acc[4][4];
#pragma unroll
  for (int mt = 0; mt < 4; ++mt)
#pragma unroll
    for (int nt = 0; nt < 4; ++nt) acc[mt][nt] = (float4v){0.f, 0.f, 0.f, 0.f};

#pragma unroll
  for (int kc = 0; kc < 8; ++kc) {
    const int kcg = kblk * 8 + kc;
    half8 b[4];
#pragma unroll
    for (int nt = 0; nt < 4; ++nt)
      b[nt] = *(const half8*)&bt[((kc * 4 + nt) * 64 + lane) * 8];
#pragma unroll
    for (int mt = 0; mt < 4; ++mt) {
      const _Float16* ap = w1s + ((size_t)((wave * 4 + mt) * 256 + kcg)) * 512 + lane * 8;
      half8 ah = *(const half8*)ap;
      half8 al = *(const half8*)(ap + (size_t)16 * 256 * 512);
#pragma unroll
      for (int nt = 0; nt < 4; ++nt) {
        acc[mt][nt] = __builtin_amdgcn_mfma_f32_16x16x32_f16(ah, b[nt],
                                                             acc[mt][nt], 0, 0, 0);
        acc[mt][nt] = __builtin_amdgcn_mfma_f32_16x16x32_f16(al, b[nt],
                                                             acc[mt][nt], 0, 0, 0);
      }
    }
  }

  const int n16 = lane & 15, quad = lane >> 4;
  float* pp = part + (size_t)kblk * (1024 * 256);
#pragma unroll
  for (int mt = 0; mt < 4; ++mt)
#pragma unroll
    for (int nt = 0; nt < 4; ++nt) {
      int s = sb + nt * 16 + n16;
      int ob = wave * 64 + mt * 16 + quad * 4;
      float4 v = {0.25f * acc[mt][nt][0], 0.25f * acc[mt][nt][1],
                  0.25f * acc[mt][nt][2], 0.25f * acc[mt][nt][3]};
      *(float4*)&pp[(size_t)s * 256 + ob] = v;
    }
}

// ---------------------------------------------------------------- LIF recurrence
// Also performs the fc1 K-split reduction (part -> cur3, in LDS).
__global__ __launch_bounds__(512, 2) void k_lif(const float* __restrict__ part,
                                                const float* __restrict__ b1,
                                                const float* __restrict__ w2,   // [128][256]
                                                const float* __restrict__ b2,
                                                const float* __restrict__ w3,   // [10][128]
                                                const float* __restrict__ b3,
                                                float* __restrict__ out) {
  __shared__ float cur3l[1024];     // [s4][o256]
  __shared__ _Float16 spk3[1152];   // [oct32][s4][8] + pad
  __shared__ _Float16 spk4[640];    // [oct16][s4][8] + pad
  const int t = threadIdx.x;
  const int sb = blockIdx.x * 4;    // 4 samples/block, grid 256 = 1 block/CU
  const int lane = t & 63;
  const int wave = __builtin_amdgcn_readfirstlane(t >> 6);
  const int n16 = lane & 15;
  const int quad = lane >> 4;

  // ---- fc1 reduce: deterministic kb-order sum + bias-last
#pragma unroll
  for (int r = 0; r < 2; ++r) {
    int v = t + r * 512;            // = s*256 + o
    int s = v >> 8, o = v & 255;
    float sum = 0.0f;
    for (int kb = 0; kb < 32; ++kb)
      sum += part[(size_t)kb * (1024 * 256) + (size_t)(sb + s) * 256 + o];
    cur3l[v] = sum + b1[o];
  }

  // ---- fc2 A-frags: A[m=lane&15][k=quad*8+jj], hi/lo exact split
  half8 a2h[8], a2l[8];
  {
    const float* wr = w2 + (size_t)(wave * 16 + n16) * 256 + quad * 8;
#pragma unroll
    for (int kt = 0; kt < 8; ++kt) {
      float4 u0 = *(const float4*)(wr + kt * 32);
      float4 u1 = *(const float4*)(wr + kt * 32 + 4);
      float wv[8] = {u0.x, u0.y, u0.z, u0.w, u1.x, u1.y, u1.z, u1.w};
#pragma unroll
      for (int e = 0; e < 8; ++e) {
        float hi = (float)(_Float16)wv[e];
        a2h[kt][e] = (_Float16)wv[e];
        a2l[kt][e] = (_Float16)(wv[e] - hi);
      }
    }
  }
  const float4 b2v = *(const float4*)(b2 + wave * 16 + quad * 4);
  float mem4[4] = {0.f, 0.f, 0.f, 0.f};

  // ---- fc3 A-frags (wave 0), rows >= 10 zero
  half8 a3h[4], a3l[4];
#pragma unroll
  for (int kt = 0; kt < 4; ++kt) { a3h[kt] = (half8){}; a3l[kt] = (half8){}; }
  if (n16 < 10) {
    const float* wr = w3 + (size_t)n16 * 128 + quad * 8;
#pragma unroll
    for (int kt = 0; kt < 4; ++kt) {
      float4 u0 = *(const float4*)(wr + kt * 32);
      float4 u1 = *(const float4*)(wr + kt * 32 + 4);
      float wv[8] = {u0.x, u0.y, u0.z, u0.w, u1.x, u1.y, u1.z, u1.w};
#pragma unroll
      for (int e = 0; e < 8; ++e) {
        float hi = (float)(_Float16)wv[e];
        a3h[kt][e] = (_Float16)wv[e];
        a3l[kt][e] = (_Float16)(wv[e] - hi);
      }
    }
  }
  float b3r[4];
#pragma unroll
  for (int r = 0; r < 4; ++r) {
    int cls = quad * 4 + r;
    b3r[r] = (cls < 10) ? b3[cls] : 0.0f;
  }
  float mem5[4] = {0.f, 0.f, 0.f, 0.f};

  __syncthreads();

  // ---- phase-1 state: threads 0..127, thread = (oct o = t>>2, sample s = t&3)
  float mem3[8], cur3r[8];
  if (t < 128) {
    const int o = t >> 2, s = t & 3;
    const float* cp = &cur3l[s * 256 + o * 8];
    float4 c0 = *(const float4*)cp;
    float4 c1 = *(const float4*)(cp + 4);
    cur3r[0] = c0.x; cur3r[1] = c0.y; cur3r[2] = c0.z; cur3r[3] = c0.w;
    cur3r[4] = c1.x; cur3r[5] = c1.y; cur3r[6] = c1.z; cur3r[7] = c1.w;
#pragma unroll
    for (int j = 0; j < 8; ++j) mem3[j] = 0.0f;
  }

  for (int step = 0; step < NSTEP; ++step) {
    if (t < 128) {
      const int o = t >> 2, s = t & 3;
      half8 sv;
#pragma unroll
      for (int j = 0; j < 8; ++j) {
        mem3[j] = lif_update(mem3[j], cur3r[j]);
        sv[j] = (_Float16)((mem3[j] > 1.0f) ? 1.0f : 0.0f);
      }
      *(half8*)&spk3[o * 32 + s * 8] = sv;
    }
    __syncthreads();
    {
      float4v acc0 = {0.f, 0.f, 0.f, 0.f}, acc1 = {0.f, 0.f, 0.f, 0.f};
#pragma unroll
      for (int kt = 0; kt < 8; ++kt) {
        half8 b = *(const half8*)&spk3[(kt * 4 + quad) * 32 + n16 * 8];
        acc0 = __builtin_amdgcn_mfma_f32_16x16x32_f16(a2h[kt], b, acc0, 0, 0, 0);
        acc1 = __builtin_amdgcn_mfma_f32_16x16x32_f16(a2l[kt], b, acc1, 0, 0, 0);
      }
      if (n16 < 4) {
        half4v pk;
#pragma unroll
        for (int r = 0; r < 4; ++r) {
          float cur4 = (acc0[r] + acc1[r]) + b2v[r];
          mem4[r] = lif_update(mem4[r], cur4);
          pk[r] = (_Float16)((mem4[r] > 1.0f) ? 1.0f : 0.0f);
        }
        *(half4v*)&spk4[(wave * 2 + (quad >> 1)) * 32 + n16 * 8 + (quad & 1) * 4] = pk;
      }
    }
    __syncthreads();
    if (wave == 0) {
      float4v c0 = {0.f, 0.f, 0.f, 0.f}, c1 = {0.f, 0.f, 0.f, 0.f};
#pragma unroll
      for (int kt = 0; kt < 4; ++kt) {
        half8 b = *(const half8*)&spk4[(kt * 4 + quad) * 32 + n16 * 8];
        c0 = __builtin_amdgcn_mfma_f32_16x16x32_f16(a3h[kt], b, c0, 0, 0, 0);
        c1 = __builtin_amdgcn_mfma_f32_16x16x32_f16(a3l[kt], b, c1, 0, 0, 0);
      }
#pragma unroll
      for (int r = 0; r < 4; ++r) {
        int cls = quad * 4 + r;
        float cur5 = (c0[r] + c1[r]) + b3r[r];
        mem5[r] = lif_update(mem5[r], cur5);
        if (n16 < 4 && cls < 10)
          out[(size_t)step * 10240 + (size_t)(sb + n16) * 10 + cls] =
              (mem5[r] > 1.0f) ? 1.0f : 0.0f;
      }
    }
    __syncthreads();
  }
}

// ---------------------------------------------------------------- launcher
extern "C" void kernel_launch(void* const* d_in, const int* in_sizes, int n_in,
                              void* d_out, int out_size, void* d_ws, size_t ws_size,
                              hipStream_t stream) {
  (void)in_sizes; (void)n_in; (void)out_size; (void)ws_size;
  const float* x   = (const float*)d_in[0];
  const float* w1c = (const float*)d_in[1];
  const float* b1c = (const float*)d_in[2];
  const float* w2c = (const float*)d_in[3];
  const float* b2c = (const float*)d_in[4];
  const float* fw1 = (const float*)d_in[5];
  const float* fb1 = (const float*)d_in[6];
  const float* fw2 = (const float*)d_in[7];
  const float* fb2 = (const float*)d_in[8];
  const float* fw3 = (const float*)d_in[9];
  const float* fb3 = (const float*)d_in[10];
  float* out = (float*)d_out;

  char* ws = (char*)d_ws;
  float*    part  = (float*)ws;                       // 32 MB
  uint8_t*  c1q   = (uint8_t*)ws;                     // 16.8 MB, aliases part
  uint8_t*  xq    = (uint8_t*)(ws + (32u << 20));     //  8 MB
  _Float16* afrag = (_Float16*)(ws + (41u << 20));    // 72 KB
  _Float16* w1s   = (_Float16*)(ws + (42u << 20));    //  8 MB

  k_pc1<<<dim3(2120), dim3(256), 0, stream>>>(x, w1c, b1c, c1q, w2c, fw1, afrag, w1s);
  k_conv2<<<dim3(1024), dim3(256), 0, stream>>>(c1q, afrag, b2c, xq);
  k_fc1<<<dim3(512), dim3(256), 0, stream>>>(xq, w1s, part);
  k_lif<<<dim3(256), dim3(512), 0, stream>>>(part, fb1, fw2, fb2, fw3, fb3, out);
}

// Round 4
// 205.898 us; speedup vs baseline: 1.0774x; 1.0774x over previous
//
#include <hip/hip_runtime.h>
#include <stdint.h>

// AudioSNN: conv1(1->32)+spike+pool -> conv2(32->64)+spike+pool -> fc1
// -> 25-step LIF (fc2, fc3).
// conv2, fc1, fc2/fc3 all run on MFMA: activations/spikes are exact small
// integers (exact fp16), weights use an exact 2-way fp16 split (err ~2^-22).
// R10: recovery from R9's regression (persistent pipeline: VGPR 64->128,
// LDS 30->60KB, occ 18%, MfmaUtil 21% -> 66us). Restores the best-measured
// conv2 (R8 half-sample, 45us) verbatim, and adds two zero-risk locality
// moves:
//   - k_pc1 runs prep blocks FIRST, conv1 blocks LAST -> c1q is the newest
//     data in L2 when conv2 starts (previously w1s prep traffic flushed it).
//   - conv2 block mapping s = bid&1023, h = bid>>10 puts both halves of
//     sample s on XCD s%8 == the XCD that produced c1q[s] (conv1 block
//     1096+s, 1096%8==0) -> c1q reads become same-XCD L2 hits.
// NOTE (R9 post-mortem): WRITE_SIZE ~26-32MB is L2 dirty-writeback
// attribution, not RMW -- do not chase it. fc1/lif summation order is
// frozen (spike thresholds are ulp-sensitive).
//
// ws layout:
//   part f32 [32][1024][256]       @0     32 MB   (c1q u8 [1024][512][32]
//                                                  aliases the first 16.8 MB
//                                                  during the conv stage)
//   xq   u8  [1024][8192]          @32M    8 MB
//   afrag f16 [9][4][2][512]       @41M   72 KB  (conv2 A fragments hi/lo)
//   w1s  f16 [2][16][256][512]     @42M    8 MB  (fc1 A fragments hi/lo planes)

#define NSTEP 25

using half8   = __attribute__((ext_vector_type(8))) _Float16;
using half4v  = __attribute__((ext_vector_type(4))) _Float16;
using float4v = __attribute__((ext_vector_type(4))) float;

__device__ __forceinline__ float lif_update(float mem, float cur) {
#pragma clang fp contract(off)
  float reset = (mem > 1.0f) ? 1.0f : 0.0f;
  float m = 0.95f * mem;
  m = m + cur;
  m = m - reset;
  return m;
}

// --------------------------------------- merged weight prep + conv1
// blocks 0..71: conv2 afrag prep (9 taps x 4 mtiles x 2 splits)
// blocks 72..1095: fc1 w1s prep (4 fragment-groups per block)
// blocks 1096..2119: conv1 (pure VALU, one sample each) -- LAST so c1q is
// the newest data in L2 when k_conv2 launches.
__global__ __launch_bounds__(256, 4) void k_pc1(const float* __restrict__ x,
                                                const float* __restrict__ w1c,
                                                const float* __restrict__ b1c,
                                                uint8_t* __restrict__ c1q,
                                                const float* __restrict__ w2c,
                                                const float* __restrict__ w1,
                                                _Float16* __restrict__ afrag,
                                                _Float16* __restrict__ w1s) {
  __shared__ float xin[66 * 34];          // conv1 input + halo
  __shared__ float wl[288];
  __shared__ float bl[32];
  const int t = threadIdx.x;
  const int b = blockIdx.x;

  if (b < 72) {                           // ---- afrag prep
    if (t < 64) {
      const int tp = b >> 3;
      const int mt = (b & 7) >> 1;
      const int sp = b & 1;
      const int m = t & 15, quad = t >> 4;
#pragma unroll
      for (int j = 0; j < 8; ++j) {
        int ch = quad * 8 + j;
        int oc = mt * 16 + m;
        float wv = w2c[(size_t)(oc * 32 + ch) * 9 + tp];
        float hi = (float)(_Float16)wv;
        _Float16 val = (sp == 0) ? (_Float16)wv : (_Float16)(wv - hi);
        afrag[(size_t)b * 512 + t * 8 + j] = val;
      }
    }
    return;
  }
  if (b < 1096) {                         // ---- w1s prep
    const int W = (b - 72) * 4 + (t >> 6);  // 0..4095 = mt*256+kcg
    const int lane = t & 63;
    const int mt = W >> 8, kcg = W & 255;
    const int m = lane & 15, quad = lane >> 4;
    const float* src = w1 + (size_t)(mt * 16 + m) * 8192 + kcg * 32 + quad * 8;
    float4 u0 = *(const float4*)src;
    float4 u1 = *(const float4*)(src + 4);
    float wv[8] = {u0.x, u0.y, u0.z, u0.w, u1.x, u1.y, u1.z, u1.w};
    half8 hi, lo;
#pragma unroll
    for (int e = 0; e < 8; ++e) {
      float h = (float)(_Float16)wv[e];
      hi[e] = (_Float16)wv[e];
      lo[e] = (_Float16)(wv[e] - h);
    }
    _Float16* dst = w1s + ((size_t)W) * 512 + lane * 8;
    *(half8*)dst = hi;
    *(half8*)(dst + (size_t)16 * 256 * 512) = lo;   // lo plane at +4 MB
    return;
  }

  // ---- conv1 path (pure VALU, one sample); 1096 % 8 == 0 keeps XCD of
  // sample s equal to s % 8.
  const int s = b - 1096;
  for (int idx = t; idx < 66 * 34; idx += 256) xin[idx] = 0.0f;
  wl[t] = w1c[t];
  if (t < 32) { wl[256 + t] = w1c[256 + t]; bl[t] = b1c[t]; }
  __syncthreads();

  const float* xs = x + (size_t)s * (64 * 32);
#pragma unroll
  for (int r = 0; r < 2; ++r) {
    int idx = t + r * 256;
    int y = idx >> 3, q = idx & 7;
    float4 v = *(const float4*)(xs + y * 32 + q * 4);
    float* dst = &xin[(y + 1) * 34 + q * 4 + 1];
    dst[0] = v.x; dst[1] = v.y; dst[2] = v.z; dst[3] = v.w;
  }
  __syncthreads();

  const int ch = t & 31;
  const int po = t >> 5;
  float wc[9];
#pragma unroll
  for (int i = 0; i < 9; ++i) wc[i] = wl[ch * 9 + i];
  const float bv = bl[ch];
  uint8_t* cs = c1q + (size_t)s * 16384;
  for (int rr = 0; rr < 64; ++rr) {
    int pos = rr * 8 + po;
    int py = pos >> 4, px = pos & 15;
    float p[4][4];
#pragma unroll
    for (int rw = 0; rw < 4; ++rw) {
      float2 a = *(const float2*)&xin[(2 * py + rw) * 34 + 2 * px];
      float2 bq = *(const float2*)&xin[(2 * py + rw) * 34 + 2 * px + 2];
      p[rw][0] = a.x; p[rw][1] = a.y; p[rw][2] = bq.x; p[rw][3] = bq.y;
    }
    int cnt = 0;
#pragma unroll
    for (int dy = 0; dy < 2; ++dy)
#pragma unroll
      for (int dx = 0; dx < 2; ++dx) {
        float acc = 0.0f;
#pragma unroll
        for (int ky = 0; ky < 3; ++ky)
#pragma unroll
          for (int kx = 0; kx < 3; ++kx)
            acc += wc[ky * 3 + kx] * p[dy + ky][dx + kx];
        float v = acc + bv;
        cnt += (v > 1.0f) ? 1 : 0;
      }
    cs[pos * 32 + ch] = (uint8_t)cnt;
  }
}

// -------------------------------------------- conv2 (pure MFMA, half sample)
// Implicit GEMM: M=64 oc, N=256 pos (half a sample), K=32 ch x 9 taps, hi/lo.
// 256 thr = 4 waves; wave w owns pre-pool local rows w*4..w*4+3 (acc[4][4]).
// cin 25.9 KB + cnt 4 KB -> 4 blocks/CU resident; grid 2048 = 2 full rounds.
// Block mapping s = bid & 1023, h = bid >> 10: both halves of sample s land
// on XCD s%8 == producer's XCD (c1q reads become same-XCD L2 hits).
__global__ __launch_bounds__(256, 4) void k_conv2(const uint8_t* __restrict__ c1q,
                                                  const _Float16* __restrict__ afrag,
                                                  const float* __restrict__ b2c,
                                                  uint8_t* __restrict__ xq) {
  __shared__ _Float16 cin[18 * 18 * 40];  // [row18][col18][ch pad40] 25920 B
  __shared__ uint8_t cnt[64 * 64];        // [oc][py_loc*8+px] epilogue staging
  const int t = threadIdx.x;
  const int bid = blockIdx.x;
  const int s = bid & 1023;
  const int h = bid >> 10;                // half: pooled rows h*8..h*8+7
  const int gr0 = h * 16 - 1;             // global pre-pool row of cin row 0

  // issue stage loads early (overlap the zero-fill)
  uint4 u0a, u1a, u0b, u1b;
  bool va = false, vb = false;
  {
    const int lr = t >> 4, px = t & 15, gr = gr0 + lr;
    if (gr >= 0 && gr < 32) {
      const uint8_t* p = c1q + (size_t)s * 16384 + (size_t)(gr * 16 + px) * 32;
      u0a = *(const uint4*)p; u1a = *(const uint4*)(p + 16); va = true;
    }
  }
  if (t < 32) {
    const int pidx = 256 + t;
    const int lr = pidx >> 4, px = pidx & 15, gr = gr0 + lr;
    if (gr >= 0 && gr < 32) {
      const uint8_t* p = c1q + (size_t)s * 16384 + (size_t)(gr * 16 + px) * 32;
      u0b = *(const uint4*)p; u1b = *(const uint4*)(p + 16); vb = true;
    }
  }

  {  // zero cin (covers halo rows/cols and ch pad)
    half8* cp = (half8*)cin;
    half8 z = {};
#pragma unroll
    for (int r = 0; r < 7; ++r) {
      int idx = t + r * 256;
      if (idx < 1620) cp[idx] = z;
    }
  }
  __syncthreads();

  {  // u8 -> fp16 interior fill (cols 1..16; invalid rows stay zero)
    if (va) {
      const int lr = t >> 4, px = t & 15;
      uint32_t wd[8] = {u0a.x, u0a.y, u0a.z, u0a.w, u1a.x, u1a.y, u1a.z, u1a.w};
      _Float16* dst = &cin[(lr * 18 + px + 1) * 40];
#pragma unroll
      for (int g = 0; g < 4; ++g) {
        half8 hv;
#pragma unroll
        for (int e = 0; e < 8; ++e) {
          uint32_t word = wd[g * 2 + (e >> 2)];
          hv[e] = (_Float16)(unsigned short)((word >> ((e & 3) * 8)) & 0xffu);
        }
        *(half8*)(dst + g * 8) = hv;
      }
    }
    if (vb) {
      const int pidx = 256 + t;
      const int lr = pidx >> 4, px = pidx & 15;
      uint32_t wd[8] = {u0b.x, u0b.y, u0b.z, u0b.w, u1b.x, u1b.y, u1b.z, u1b.w};
      _Float16* dst = &cin[(lr * 18 + px + 1) * 40];
#pragma unroll
      for (int g = 0; g < 4; ++g) {
        half8 hv;
#pragma unroll
        for (int e = 0; e < 8; ++e) {
          uint32_t word = wd[g * 2 + (e >> 2)];
          hv[e] = (_Float16)(unsigned short)((word >> ((e & 3) * 8)) & 0xffu);
        }
        *(half8*)(dst + g * 8) = hv;
      }
    }
  }
  __syncthreads();

  const int lane = t & 63;
  const int wave = __builtin_amdgcn_readfirstlane(t >> 6);  // 0..3
  const int xlane = lane & 15, quad = lane >> 4;

  float4v acc[4][4];
#pragma unroll
  for (int mt = 0; mt < 4; ++mt)
#pragma unroll
    for (int nt = 0; nt < 4; ++nt) acc[mt][nt] = (float4v){0.f, 0.f, 0.f, 0.f};

#pragma unroll
  for (int ky = 0; ky < 3; ++ky)
#pragma unroll
    for (int kx = 0; kx < 3; ++kx) {
      const int tp = ky * 3 + kx;
      half8 b[4];
#pragma unroll
      for (int nt = 0; nt < 4; ++nt) {
        int row = wave * 4 + nt + ky;      // 0..17
        int col = xlane + kx;              // 0..17
        b[nt] = *(const half8*)&cin[(row * 18 + col) * 40 + quad * 8];
      }
#pragma unroll
      for (int mt = 0; mt < 4; ++mt) {
        half8 ah = *(const half8*)(afrag +
                     ((size_t)((tp * 4 + mt) * 2 + 0)) * 512 + lane * 8);
        half8 al = *(const half8*)(afrag +
                     ((size_t)((tp * 4 + mt) * 2 + 1)) * 512 + lane * 8);
#pragma unroll
        for (int nt = 0; nt < 4; ++nt) {
          acc[mt][nt] = __builtin_amdgcn_mfma_f32_16x16x32_f16(ah, b[nt],
                                                               acc[mt][nt], 0, 0, 0);
          acc[mt][nt] = __builtin_amdgcn_mfma_f32_16x16x32_f16(al, b[nt],
                                                               acc[mt][nt], 0, 0, 0);
        }
      }
    }

  float bw[4][4];
#pragma unroll
  for (int mt = 0; mt < 4; ++mt)
#pragma unroll
    for (int r = 0; r < 4; ++r) bw[mt][r] = b2c[mt * 16 + quad * 4 + r];

  // pool + spike-count into LDS (scattered u8, cheap), then coalesced stores
  const int px = xlane >> 1;
  const bool writer = (xlane & 1) == 0;
#pragma unroll
  for (int mt = 0; mt < 4; ++mt)
#pragma unroll
    for (int ntp = 0; ntp < 2; ++ntp) {
      int py = wave * 2 + ntp;             // pooled row within half (0..7)
#pragma unroll
      for (int r = 0; r < 4; ++r) {
        float v0 = 0.25f * acc[mt][2 * ntp + 0][r] + bw[mt][r];
        float v1 = 0.25f * acc[mt][2 * ntp + 1][r] + bw[mt][r];
        int c = ((v0 > 1.0f) ? 1 : 0) + ((v1 > 1.0f) ? 1 : 0);
        c += __shfl_xor(c, 1, 64);
        if (writer) {
          int oc = mt * 16 + quad * 4 + r;
          cnt[oc * 64 + py * 8 + px] = (uint8_t)c;
        }
      }
    }
  __syncthreads();

  // coalesced write-out: thread t -> oc = t>>2, seg = t&3 (16 B each)
  {
    uint4 v = *(const uint4*)&cnt[(t >> 2) * 64 + (t & 3) * 16];
    *(uint4*)(xq + (size_t)s * 8192 + (size_t)(t >> 2) * 128 + h * 64 +
              (t & 3) * 16) = v;
  }
}

// ---------------------------------------------------------------- fc1 (MFMA)
__global__ __launch_bounds__(256, 2) void k_fc1(const uint8_t* __restrict__ xq,
                                                const _Float16* __restrict__ w1s,
                                                float* __restrict__ part) {
  __shared__ _Float16 bt[8 * 4 * 64 * 8];   // [kc][nt][lane][8] = 32 KB
  const int t = threadIdx.x;
  const int sblk = blockIdx.x >> 5;   // 16 sample tiles of 64
  const int kblk = blockIdx.x & 31;   // 32 K slices of 256
  const int sb = sblk * 64;

  {  // stage B: u8 counts -> fp16, frag-ready
    const int row = t >> 2;
    const int seg = t & 3;
    const int nt = row >> 4, n16 = row & 15;
    const uint8_t* src = xq + (size_t)(sb + row) * 8192 + kblk * 256 + seg * 64;
#pragma unroll
    for (int q = 0; q < 4; ++q) {
      uint4 u = *(const uint4*)(src + q * 16);
      uint32_t wd[4] = {u.x, u.y, u.z, u.w};
#pragma unroll
      for (int g = 0; g < 2; ++g) {
        half8 h;
#pragma unroll
        for (int e = 0; e < 8; ++e) {
          uint32_t word = wd[g * 2 + (e >> 2)];
          h[e] = (_Float16)(unsigned short)((word >> ((e & 3) * 8)) & 0xffu);
        }
        int koff = seg * 64 + q * 16 + g * 8;
        int kc = koff >> 5, quad = (koff >> 3) & 3;
        *(half8*)&bt[(((kc * 4 + nt) * 64) + quad * 16 + n16) * 8] = h;
      }
    }
  }
  __syncthreads();

  const int lane = t & 63;
  const int wave = __builtin_amdgcn_readfirstlane(t >> 6);

  float4v acc[4][4];
#pragma unroll
  for (int mt = 0; mt < 4; ++mt)
#pragma unroll
    for (int nt = 0; nt < 4; ++nt) acc[mt][nt] = (float4v){0.f, 0.f, 0.f, 0.f};

#pragma unroll
  for (int kc = 0; kc < 8; ++kc) {
    const int kcg = kblk * 8 + kc;
    half8 b[4];
#pragma unroll
    for (int nt = 0; nt < 4; ++nt)
      b[nt] = *(const half8*)&bt[((kc * 4 + nt) * 64 + lane) * 8];
#pragma unroll
    for (int mt = 0; mt < 4; ++mt) {
      const _Float16* ap = w1s + ((size_t)((wave * 4 + mt) * 256 + kcg)) * 512 + lane * 8;
      half8 ah = *(const half8*)ap;
      half8 al = *(const half8*)(ap + (size_t)16 * 256 * 512);
#pragma unroll
      for (int nt = 0; nt < 4; ++nt) {
        acc[mt][nt] = __builtin_amdgcn_mfma_f32_16x16x32_f16(ah, b[nt],
                                                             acc[mt][nt], 0, 0, 0);
        acc[mt][nt] = __builtin_amdgcn_mfma_f32_16x16x32_f16(al, b[nt],
                                                             acc[mt][nt], 0, 0, 0);
      }
    }
  }

  const int n16 = lane & 15, quad = lane >> 4;
  float* pp = part + (size_t)kblk * (1024 * 256);
#pragma unroll
  for (int mt = 0; mt < 4; ++mt)
#pragma unroll
    for (int nt = 0; nt < 4; ++nt) {
      int s = sb + nt * 16 + n16;
      int ob = wave * 64 + mt * 16 + quad * 4;
      float4 v = {0.25f * acc[mt][nt][0], 0.25f * acc[mt][nt][1],
                  0.25f * acc[mt][nt][2], 0.25f * acc[mt][nt][3]};
      *(float4*)&pp[(size_t)s * 256 + ob] = v;
    }
}

// ---------------------------------------------------------------- LIF recurrence
// Also performs the fc1 K-split reduction (part -> cur3, in LDS).
__global__ __launch_bounds__(512, 2) void k_lif(const float* __restrict__ part,
                                                const float* __restrict__ b1,
                                                const float* __restrict__ w2,   // [128][256]
                                                const float* __restrict__ b2,
                                                const float* __restrict__ w3,   // [10][128]
                                                const float* __restrict__ b3,
                                                float* __restrict__ out) {
  __shared__ float cur3l[1024];     // [s4][o256]
  __shared__ _Float16 spk3[1152];   // [oct32][s4][8] + pad
  __shared__ _Float16 spk4[640];    // [oct16][s4][8] + pad
  const int t = threadIdx.x;
  const int sb = blockIdx.x * 4;    // 4 samples/block, grid 256 = 1 block/CU
  const int lane = t & 63;
  const int wave = __builtin_amdgcn_readfirstlane(t >> 6);
  const int n16 = lane & 15;
  const int quad = lane >> 4;

  // ---- fc1 reduce: deterministic kb-order sum + bias-last
#pragma unroll
  for (int r = 0; r < 2; ++r) {
    int v = t + r * 512;            // = s*256 + o
    int s = v >> 8, o = v & 255;
    float sum = 0.0f;
    for (int kb = 0; kb < 32; ++kb)
      sum += part[(size_t)kb * (1024 * 256) + (size_t)(sb + s) * 256 + o];
    cur3l[v] = sum + b1[o];
  }

  // ---- fc2 A-frags: A[m=lane&15][k=quad*8+jj], hi/lo exact split
  half8 a2h[8], a2l[8];
  {
    const float* wr = w2 + (size_t)(wave * 16 + n16) * 256 + quad * 8;
#pragma unroll
    for (int kt = 0; kt < 8; ++kt) {
      float4 u0 = *(const float4*)(wr + kt * 32);
      float4 u1 = *(const float4*)(wr + kt * 32 + 4);
      float wv[8] = {u0.x, u0.y, u0.z, u0.w, u1.x, u1.y, u1.z, u1.w};
#pragma unroll
      for (int e = 0; e < 8; ++e) {
        float hi = (float)(_Float16)wv[e];
        a2h[kt][e] = (_Float16)wv[e];
        a2l[kt][e] = (_Float16)(wv[e] - hi);
      }
    }
  }
  const float4 b2v = *(const float4*)(b2 + wave * 16 + quad * 4);
  float mem4[4] = {0.f, 0.f, 0.f, 0.f};

  // ---- fc3 A-frags (wave 0), rows >= 10 zero
  half8 a3h[4], a3l[4];
#pragma unroll
  for (int kt = 0; kt < 4; ++kt) { a3h[kt] = (half8){}; a3l[kt] = (half8){}; }
  if (n16 < 10) {
    const float* wr = w3 + (size_t)n16 * 128 + quad * 8;
#pragma unroll
    for (int kt = 0; kt < 4; ++kt) {
      float4 u0 = *(const float4*)(wr + kt * 32);
      float4 u1 = *(const float4*)(wr + kt * 32 + 4);
      float wv[8] = {u0.x, u0.y, u0.z, u0.w, u1.x, u1.y, u1.z, u1.w};
#pragma unroll
      for (int e = 0; e < 8; ++e) {
        float hi = (float)(_Float16)wv[e];
        a3h[kt][e] = (_Float16)wv[e];
        a3l[kt][e] = (_Float16)(wv[e] - hi);
      }
    }
  }
  float b3r[4];
#pragma unroll
  for (int r = 0; r < 4; ++r) {
    int cls = quad * 4 + r;
    b3r[r] = (cls < 10) ? b3[cls] : 0.0f;
  }
  float mem5[4] = {0.f, 0.f, 0.f, 0.f};

  __syncthreads();

  // ---- phase-1 state: threads 0..127, thread = (oct o = t>>2, sample s = t&3)
  float mem3[8], cur3r[8];
  if (t < 128) {
    const int o = t >> 2, s = t & 3;
    const float* cp = &cur3l[s * 256 + o * 8];
    float4 c0 = *(const float4*)cp;
    float4 c1 = *(const float4*)(cp + 4);
    cur3r[0] = c0.x; cur3r[1] = c0.y; cur3r[2] = c0.z; cur3r[3] = c0.w;
    cur3r[4] = c1.x; cur3r[5] = c1.y; cur3r[6] = c1.z; cur3r[7] = c1.w;
#pragma unroll
    for (int j = 0; j < 8; ++j) mem3[j] = 0.0f;
  }

  for (int step = 0; step < NSTEP; ++step) {
    if (t < 128) {
      const int o = t >> 2, s = t & 3;
      half8 sv;
#pragma unroll
      for (int j = 0; j < 8; ++j) {
        mem3[j] = lif_update(mem3[j], cur3r[j]);
        sv[j] = (_Float16)((mem3[j] > 1.0f) ? 1.0f : 0.0f);
      }
      *(half8*)&spk3[o * 32 + s * 8] = sv;
    }
    __syncthreads();
    {
      float4v acc0 = {0.f, 0.f, 0.f, 0.f}, acc1 = {0.f, 0.f, 0.f, 0.f};
#pragma unroll
      for (int kt = 0; kt < 8; ++kt) {
        half8 b = *(const half8*)&spk3[(kt * 4 + quad) * 32 + n16 * 8];
        acc0 = __builtin_amdgcn_mfma_f32_16x16x32_f16(a2h[kt], b, acc0, 0, 0, 0);
        acc1 = __builtin_amdgcn_mfma_f32_16x16x32_f16(a2l[kt], b, acc1, 0, 0, 0);
      }
      if (n16 < 4) {
        half4v pk;
#pragma unroll
        for (int r = 0; r < 4; ++r) {
          float cur4 = (acc0[r] + acc1[r]) + b2v[r];
          mem4[r] = lif_update(mem4[r], cur4);
          pk[r] = (_Float16)((mem4[r] > 1.0f) ? 1.0f : 0.0f);
        }
        *(half4v*)&spk4[(wave * 2 + (quad >> 1)) * 32 + n16 * 8 + (quad & 1) * 4] = pk;
      }
    }
    __syncthreads();
    if (wave == 0) {
      float4v c0 = {0.f, 0.f, 0.f, 0.f}, c1 = {0.f, 0.f, 0.f, 0.f};
#pragma unroll
      for (int kt = 0; kt < 4; ++kt) {
        half8 b = *(const half8*)&spk4[(kt * 4 + quad) * 32 + n16 * 8];
        c0 = __builtin_amdgcn_mfma_f32_16x16x32_f16(a3h[kt], b, c0, 0, 0, 0);
        c1 = __builtin_amdgcn_mfma_f32_16x16x32_f16(a3l[kt], b, c1, 0, 0, 0);
      }
#pragma unroll
      for (int r = 0; r < 4; ++r) {
        int cls = quad * 4 + r;
        float cur5 = (c0[r] + c1[r]) + b3r[r];
        mem5[r] = lif_update(mem5[r], cur5);
        if (n16 < 4 && cls < 10)
          out[(size_t)step * 10240 + (size_t)(sb + n16) * 10 + cls] =
              (mem5[r] > 1.0f) ? 1.0f : 0.0f;
      }
    }
    __syncthreads();
  }
}

// ---------------------------------------------------------------- launcher
extern "C" void kernel_launch(void* const* d_in, const int* in_sizes, int n_in,
                              void* d_out, int out_size, void* d_ws, size_t ws_size,
                              hipStream_t stream) {
  (void)in_sizes; (void)n_in; (void)out_size; (void)ws_size;
  const float* x   = (const float*)d_in[0];
  const float* w1c = (const float*)d_in[1];
  const float* b1c = (const float*)d_in[2];
  const float* w2c = (const float*)d_in[3];
  const float* b2c = (const float*)d_in[4];
  const float* fw1 = (const float*)d_in[5];
  const float* fb1 = (const float*)d_in[6];
  const float* fw2 = (const float*)d_in[7];
  const float* fb2 = (const float*)d_in[8];
  const float* fw3 = (const float*)d_in[9];
  const float* fb3 = (const float*)d_in[10];
  float* out = (float*)d_out;

  char* ws = (char*)d_ws;
  float*    part  = (float*)ws;                       // 32 MB
  uint8_t*  c1q   = (uint8_t*)ws;                     // 16.8 MB, aliases part
  uint8_t*  xq    = (uint8_t*)(ws + (32u << 20));     //  8 MB
  _Float16* afrag = (_Float16*)(ws + (41u << 20));    // 72 KB
  _Float16* w1s   = (_Float16*)(ws + (42u << 20));    //  8 MB

  k_pc1<<<dim3(2120), dim3(256), 0, stream>>>(x, w1c, b1c, c1q, w2c, fw1, afrag, w1s);
  k_conv2<<<dim3(2048), dim3(256), 0, stream>>>(c1q, afrag, b2c, xq);
  k_fc1<<<dim3(512), dim3(256), 0, stream>>>(xq, w1s, part);
  k_lif<<<dim3(256), dim3(512), 0, stream>>>(part, fb1, fw2, fb2, fw3, fb3, out);
}

// Round 5
// 197.425 us; speedup vs baseline: 1.1237x; 1.0429x over previous
//
#include <hip/hip_runtime.h>
#include <stdint.h>

// AudioSNN: conv1(1->32)+spike+pool -> conv2(32->64)+spike+pool -> fc1
// -> 25-step LIF (fc2, fc3).
// conv2, fc1, fc2/fc3 all run on MFMA: activations/spikes are exact small
// integers (exact fp16), weights use an exact 2-way fp16 split (err ~2^-22).
// R11: attack the two latency taxes the R4 profile exposed.
//   - k_pc1 was 49us @ VALUBusy 42%, Occ 21%, MfmaUtil 0: conv1 blocks were
//     few (1024), long (64 serial positions/thread), and dispatched AFTER
//     1096 prep blocks. Now: conv1 = 2048 half-sample blocks (32 positions/
//     thread, 5.9KB LDS) dispatched FIRST; prep blocks trail and hide in
//     conv1's tail. Same FMA order per position -> identical c1q bytes.
//   - k_lif paid 75 barrier rounds (25 steps x 3). Now 2 barriers/step:
//     fc3 is delayed one iteration (computed from spk4[i-1] at top of step i
//     by wave0, before phase1; fc2's spk4[i] writes can't race since wave0
//     reaches barrier A only after its fc3 reads). Identical arithmetic,
//     final fc3 after the loop.
// NOTE: WRITE_SIZE inflation is L2 dirty-writeback attribution, not RMW.
// fc1/lif summation order frozen (spike thresholds are ulp-sensitive).
//
// ws layout:
//   part f32 [32][1024][256]       @0     32 MB   (c1q u8 [1024][512][32]
//                                                  aliases the first 16.8 MB
//                                                  during the conv stage)
//   xq   u8  [1024][8192]          @32M    8 MB
//   afrag f16 [9][4][2][512]       @41M   72 KB  (conv2 A fragments hi/lo)
//   w1s  f16 [2][16][256][512]     @42M    8 MB  (fc1 A fragments hi/lo planes)

#define NSTEP 25

using half8   = __attribute__((ext_vector_type(8))) _Float16;
using half4v  = __attribute__((ext_vector_type(4))) _Float16;
using float4v = __attribute__((ext_vector_type(4))) float;

__device__ __forceinline__ float lif_update(float mem, float cur) {
#pragma clang fp contract(off)
  float reset = (mem > 1.0f) ? 1.0f : 0.0f;
  float m = 0.95f * mem;
  m = m + cur;
  m = m - reset;
  return m;
}

// --------------------------------------- merged conv1 + weight prep
// blocks 0..2047:    conv1 half-sample (s = b>>1, rows (b&1)*32..+31) FIRST
// blocks 2048..2119: conv2 afrag prep (9 taps x 4 mtiles x 2 splits)
// blocks 2120..3143: fc1 w1s prep (4 fragment-groups per block)
__global__ __launch_bounds__(256, 4) void k_pc1(const float* __restrict__ x,
                                                const float* __restrict__ w1c,
                                                const float* __restrict__ b1c,
                                                uint8_t* __restrict__ c1q,
                                                const float* __restrict__ w2c,
                                                const float* __restrict__ w1,
                                                _Float16* __restrict__ afrag,
                                                _Float16* __restrict__ w1s) {
  __shared__ float xin[34 * 34];          // half-sample input + halo (4.6 KB)
  __shared__ float wl[288];
  __shared__ float bl[32];
  const int t = threadIdx.x;
  const int b = blockIdx.x;

  if (b >= 2048) {                        // ---- prep paths (trail)
    const int bp = b - 2048;
    if (bp < 72) {                        // afrag prep
      if (t < 64) {
        const int tp = bp >> 3;
        const int mt = (bp & 7) >> 1;
        const int sp = bp & 1;
        const int m = t & 15, quad = t >> 4;
#pragma unroll
        for (int j = 0; j < 8; ++j) {
          int ch = quad * 8 + j;
          int oc = mt * 16 + m;
          float wv = w2c[(size_t)(oc * 32 + ch) * 9 + tp];
          float hi = (float)(_Float16)wv;
          _Float16 val = (sp == 0) ? (_Float16)wv : (_Float16)(wv - hi);
          afrag[(size_t)bp * 512 + t * 8 + j] = val;
        }
      }
      return;
    }
    {                                     // w1s prep
      const int W = (bp - 72) * 4 + (t >> 6);  // 0..4095 = mt*256+kcg
      const int lane = t & 63;
      const int mt = W >> 8, kcg = W & 255;
      const int m = lane & 15, quad = lane >> 4;
      const float* src = w1 + (size_t)(mt * 16 + m) * 8192 + kcg * 32 + quad * 8;
      float4 u0 = *(const float4*)src;
      float4 u1 = *(const float4*)(src + 4);
      float wv[8] = {u0.x, u0.y, u0.z, u0.w, u1.x, u1.y, u1.z, u1.w};
      half8 hi, lo;
#pragma unroll
      for (int e = 0; e < 8; ++e) {
        float h = (float)(_Float16)wv[e];
        hi[e] = (_Float16)wv[e];
        lo[e] = (_Float16)(wv[e] - h);
      }
      _Float16* dst = w1s + ((size_t)W) * 512 + lane * 8;
      *(half8*)dst = hi;
      *(half8*)(dst + (size_t)16 * 256 * 512) = lo;   // lo plane at +4 MB
    }
    return;
  }

  // ---- conv1 path: half a sample per block (pooled rows hh*16..hh*16+15)
  const int s = b >> 1;
  const int hh = b & 1;
  for (int idx = t; idx < 34 * 34; idx += 256) xin[idx] = 0.0f;
  wl[t] = w1c[t];
  if (t < 32) { wl[256 + t] = w1c[256 + t]; bl[t] = b1c[t]; }
  __syncthreads();

  // load 33 valid input rows: global rows [hh*32 + lr0 - 1 .. +32]
  const int lr0 = (hh == 0) ? 1 : 0;
  const float* xs = x + (size_t)s * 2048 + (size_t)(hh * 32 + lr0 - 1) * 32;
  for (int idx = t; idx < 264; idx += 256) {
    int row_i = idx >> 3, q = idx & 7;
    float4 v = *(const float4*)(xs + row_i * 32 + q * 4);
    float* dst = &xin[(lr0 + row_i) * 34 + q * 4 + 1];
    dst[0] = v.x; dst[1] = v.y; dst[2] = v.z; dst[3] = v.w;
  }
  __syncthreads();

  // LDS reads are wave-broadcast (2 distinct addrs/wave); writes coalesced.
  const int ch = t & 31;
  const int po = t >> 5;
  float wc[9];
#pragma unroll
  for (int i = 0; i < 9; ++i) wc[i] = wl[ch * 9 + i];
  const float bv = bl[ch];
  uint8_t* cs = c1q + (size_t)s * 16384 + hh * 8192;
#pragma unroll 2
  for (int rr = 0; rr < 32; ++rr) {
    int pos = rr * 8 + po;                 // local pooled pos 0..255
    int py = pos >> 4, px = pos & 15;      // local pooled row 0..15
    float p[4][4];
#pragma unroll
    for (int rw = 0; rw < 4; ++rw) {
      float2 a = *(const float2*)&xin[(2 * py + rw) * 34 + 2 * px];
      float2 bq = *(const float2*)&xin[(2 * py + rw) * 34 + 2 * px + 2];
      p[rw][0] = a.x; p[rw][1] = a.y; p[rw][2] = bq.x; p[rw][3] = bq.y;
    }
    int cnt = 0;
#pragma unroll
    for (int dy = 0; dy < 2; ++dy)
#pragma unroll
      for (int dx = 0; dx < 2; ++dx) {
        float acc = 0.0f;
#pragma unroll
        for (int ky = 0; ky < 3; ++ky)
#pragma unroll
          for (int kx = 0; kx < 3; ++kx)
            acc += wc[ky * 3 + kx] * p[dy + ky][dx + kx];
        float v = acc + bv;
        cnt += (v > 1.0f) ? 1 : 0;
      }
    cs[pos * 32 + ch] = (uint8_t)cnt;
  }
}

// -------------------------------------------- conv2 (pure MFMA, half sample)
// Implicit GEMM: M=64 oc, N=256 pos (half a sample), K=32 ch x 9 taps, hi/lo.
// 256 thr = 4 waves; wave w owns pre-pool local rows w*4..w*4+3 (acc[4][4]).
// cin 25.9 KB + cnt 4 KB -> 4 blocks/CU resident; grid 2048 = 2 full rounds.
__global__ __launch_bounds__(256, 4) void k_conv2(const uint8_t* __restrict__ c1q,
                                                  const _Float16* __restrict__ afrag,
                                                  const float* __restrict__ b2c,
                                                  uint8_t* __restrict__ xq) {
  __shared__ _Float16 cin[18 * 18 * 40];  // [row18][col18][ch pad40] 25920 B
  __shared__ uint8_t cnt[64 * 64];        // [oc][py_loc*8+px] epilogue staging
  const int t = threadIdx.x;
  const int bid = blockIdx.x;
  const int s = bid & 1023;
  const int h = bid >> 10;                // half: pooled rows h*8..h*8+7
  const int gr0 = h * 16 - 1;             // global pre-pool row of cin row 0

  // issue stage loads early (overlap the zero-fill)
  uint4 u0a, u1a, u0b, u1b;
  bool va = false, vb = false;
  {
    const int lr = t >> 4, px = t & 15, gr = gr0 + lr;
    if (gr >= 0 && gr < 32) {
      const uint8_t* p = c1q + (size_t)s * 16384 + (size_t)(gr * 16 + px) * 32;
      u0a = *(const uint4*)p; u1a = *(const uint4*)(p + 16); va = true;
    }
  }
  if (t < 32) {
    const int pidx = 256 + t;
    const int lr = pidx >> 4, px = pidx & 15, gr = gr0 + lr;
    if (gr >= 0 && gr < 32) {
      const uint8_t* p = c1q + (size_t)s * 16384 + (size_t)(gr * 16 + px) * 32;
      u0b = *(const uint4*)p; u1b = *(const uint4*)(p + 16); vb = true;
    }
  }

  {  // zero cin (covers halo rows/cols and ch pad)
    half8* cp = (half8*)cin;
    half8 z = {};
#pragma unroll
    for (int r = 0; r < 7; ++r) {
      int idx = t + r * 256;
      if (idx < 1620) cp[idx] = z;
    }
  }
  __syncthreads();

  {  // u8 -> fp16 interior fill (cols 1..16; invalid rows stay zero)
    if (va) {
      const int lr = t >> 4, px = t & 15;
      uint32_t wd[8] = {u0a.x, u0a.y, u0a.z, u0a.w, u1a.x, u1a.y, u1a.z, u1a.w};
      _Float16* dst = &cin[(lr * 18 + px + 1) * 40];
#pragma unroll
      for (int g = 0; g < 4; ++g) {
        half8 hv;
#pragma unroll
        for (int e = 0; e < 8; ++e) {
          uint32_t word = wd[g * 2 + (e >> 2)];
          hv[e] = (_Float16)(unsigned short)((word >> ((e & 3) * 8)) & 0xffu);
        }
        *(half8*)(dst + g * 8) = hv;
      }
    }
    if (vb) {
      const int pidx = 256 + t;
      const int lr = pidx >> 4, px = pidx & 15;
      uint32_t wd[8] = {u0b.x, u0b.y, u0b.z, u0b.w, u1b.x, u1b.y, u1b.z, u1b.w};
      _Float16* dst = &cin[(lr * 18 + px + 1) * 40];
#pragma unroll
      for (int g = 0; g < 4; ++g) {
        half8 hv;
#pragma unroll
        for (int e = 0; e < 8; ++e) {
          uint32_t word = wd[g * 2 + (e >> 2)];
          hv[e] = (_Float16)(unsigned short)((word >> ((e & 3) * 8)) & 0xffu);
        }
        *(half8*)(dst + g * 8) = hv;
      }
    }
  }
  __syncthreads();

  const int lane = t & 63;
  const int wave = __builtin_amdgcn_readfirstlane(t >> 6);  // 0..3
  const int xlane = lane & 15, quad = lane >> 4;

  float4v acc[4][4];
#pragma unroll
  for (int mt = 0; mt < 4; ++mt)
#pragma unroll
    for (int nt = 0; nt < 4; ++nt) acc[mt][nt] = (float4v){0.f, 0.f, 0.f, 0.f};

#pragma unroll
  for (int ky = 0; ky < 3; ++ky)
#pragma unroll
    for (int kx = 0; kx < 3; ++kx) {
      const int tp = ky * 3 + kx;
      half8 b[4];
#pragma unroll
      for (int nt = 0; nt < 4; ++nt) {
        int row = wave * 4 + nt + ky;      // 0..17
        int col = xlane + kx;              // 0..17
        b[nt] = *(const half8*)&cin[(row * 18 + col) * 40 + quad * 8];
      }
#pragma unroll
      for (int mt = 0; mt < 4; ++mt) {
        half8 ah = *(const half8*)(afrag +
                     ((size_t)((tp * 4 + mt) * 2 + 0)) * 512 + lane * 8);
        half8 al = *(const half8*)(afrag +
                     ((size_t)((tp * 4 + mt) * 2 + 1)) * 512 + lane * 8);
#pragma unroll
        for (int nt = 0; nt < 4; ++nt) {
          acc[mt][nt] = __builtin_amdgcn_mfma_f32_16x16x32_f16(ah, b[nt],
                                                               acc[mt][nt], 0, 0, 0);
          acc[mt][nt] = __builtin_amdgcn_mfma_f32_16x16x32_f16(al, b[nt],
                                                               acc[mt][nt], 0, 0, 0);
        }
      }
    }

  float bw[4][4];
#pragma unroll
  for (int mt = 0; mt < 4; ++mt)
#pragma unroll
    for (int r = 0; r < 4; ++r) bw[mt][r] = b2c[mt * 16 + quad * 4 + r];

  // pool + spike-count into LDS (scattered u8, cheap), then coalesced stores
  const int px = xlane >> 1;
  const bool writer = (xlane & 1) == 0;
#pragma unroll
  for (int mt = 0; mt < 4; ++mt)
#pragma unroll
    for (int ntp = 0; ntp < 2; ++ntp) {
      int py = wave * 2 + ntp;             // pooled row within half (0..7)
#pragma unroll
      for (int r = 0; r < 4; ++r) {
        float v0 = 0.25f * acc[mt][2 * ntp + 0][r] + bw[mt][r];
        float v1 = 0.25f * acc[mt][2 * ntp + 1][r] + bw[mt][r];
        int c = ((v0 > 1.0f) ? 1 : 0) + ((v1 > 1.0f) ? 1 : 0);
        c += __shfl_xor(c, 1, 64);
        if (writer) {
          int oc = mt * 16 + quad * 4 + r;
          cnt[oc * 64 + py * 8 + px] = (uint8_t)c;
        }
      }
    }
  __syncthreads();

  // coalesced write-out: thread t -> oc = t>>2, seg = t&3 (16 B each)
  {
    uint4 v = *(const uint4*)&cnt[(t >> 2) * 64 + (t & 3) * 16];
    *(uint4*)(xq + (size_t)s * 8192 + (size_t)(t >> 2) * 128 + h * 64 +
              (t & 3) * 16) = v;
  }
}

// ---------------------------------------------------------------- fc1 (MFMA)
__global__ __launch_bounds__(256, 2) void k_fc1(const uint8_t* __restrict__ xq,
                                                const _Float16* __restrict__ w1s,
                                                float* __restrict__ part) {
  __shared__ _Float16 bt[8 * 4 * 64 * 8];   // [kc][nt][lane][8] = 32 KB
  const int t = threadIdx.x;
  const int sblk = blockIdx.x >> 5;   // 16 sample tiles of 64
  const int kblk = blockIdx.x & 31;   // 32 K slices of 256
  const int sb = sblk * 64;

  {  // stage B: u8 counts -> fp16, frag-ready
    const int row = t >> 2;
    const int seg = t & 3;
    const int nt = row >> 4, n16 = row & 15;
    const uint8_t* src = xq + (size_t)(sb + row) * 8192 + kblk * 256 + seg * 64;
#pragma unroll
    for (int q = 0; q < 4; ++q) {
      uint4 u = *(const uint4*)(src + q * 16);
      uint32_t wd[4] = {u.x, u.y, u.z, u.w};
#pragma unroll
      for (int g = 0; g < 2; ++g) {
        half8 h;
#pragma unroll
        for (int e = 0; e < 8; ++e) {
          uint32_t word = wd[g * 2 + (e >> 2)];
          h[e] = (_Float16)(unsigned short)((word >> ((e & 3) * 8)) & 0xffu);
        }
        int koff = seg * 64 + q * 16 + g * 8;
        int kc = koff >> 5, quad = (koff >> 3) & 3;
        *(half8*)&bt[(((kc * 4 + nt) * 64) + quad * 16 + n16) * 8] = h;
      }
    }
  }
  __syncthreads();

  const int lane = t & 63;
  const int wave = __builtin_amdgcn_readfirstlane(t >> 6);

  float4v acc[4][4];
#pragma unroll
  for (int mt = 0; mt < 4; ++mt)
#pragma unroll
    for (int nt = 0; nt < 4; ++nt) acc[mt][nt] = (float4v){0.f, 0.f, 0.f, 0.f};

#pragma unroll
  for (int kc = 0; kc < 8; ++kc) {
    const int kcg = kblk * 8 + kc;
    half8 b[4];
#pragma unroll
    for (int nt = 0; nt < 4; ++nt)
      b[nt] = *(const half8*)&bt[((kc * 4 + nt) * 64 + lane) * 8];
#pragma unroll
    for (int mt = 0; mt < 4; ++mt) {
      const _Float16* ap = w1s + ((size_t)((wave * 4 + mt) * 256 + kcg)) * 512 + lane * 8;
      half8 ah = *(const half8*)ap;
      half8 al = *(const half8*)(ap + (size_t)16 * 256 * 512);
#pragma unroll
      for (int nt = 0; nt < 4; ++nt) {
        acc[mt][nt] = __builtin_amdgcn_mfma_f32_16x16x32_f16(ah, b[nt],
                                                             acc[mt][nt], 0, 0, 0);
        acc[mt][nt] = __builtin_amdgcn_mfma_f32_16x16x32_f16(al, b[nt],
                                                             acc[mt][nt], 0, 0, 0);
      }
    }
  }

  const int n16 = lane & 15, quad = lane >> 4;
  float* pp = part + (size_t)kblk * (1024 * 256);
#pragma unroll
  for (int mt = 0; mt < 4; ++mt)
#pragma unroll
    for (int nt = 0; nt < 4; ++nt) {
      int s = sb + nt * 16 + n16;
      int ob = wave * 64 + mt * 16 + quad * 4;
      float4 v = {0.25f * acc[mt][nt][0], 0.25f * acc[mt][nt][1],
                  0.25f * acc[mt][nt][2], 0.25f * acc[mt][nt][3]};
      *(float4*)&pp[(size_t)s * 256 + ob] = v;
    }
}

// ---------------------------------------------------------------- LIF recurrence
// Also performs the fc1 K-split reduction (part -> cur3, in LDS).
// R11: 2 barriers/step. fc3 for step i-1 runs at the top of step i (wave 0,
// reading spk4[i-1], visible since the last barrier); phase1 follows on the
// same wave, so fc2's spk4[i] writes (after barrier A) cannot race fc3's
// reads. Arithmetic identical; final fc3 after the loop.
__global__ __launch_bounds__(512, 2) void k_lif(const float* __restrict__ part,
                                                const float* __restrict__ b1,
                                                const float* __restrict__ w2,   // [128][256]
                                                const float* __restrict__ b2,
                                                const float* __restrict__ w3,   // [10][128]
                                                const float* __restrict__ b3,
                                                float* __restrict__ out) {
  __shared__ float cur3l[1024];     // [s4][o256]
  __shared__ _Float16 spk3[1152];   // [oct32][s4][8] + pad
  __shared__ _Float16 spk4[640];    // [oct16][s4][8] + pad
  const int t = threadIdx.x;
  const int sb = blockIdx.x * 4;    // 4 samples/block, grid 256 = 1 block/CU
  const int lane = t & 63;
  const int wave = __builtin_amdgcn_readfirstlane(t >> 6);
  const int n16 = lane & 15;
  const int quad = lane >> 4;

  // ---- fc1 reduce: deterministic kb-order sum + bias-last
#pragma unroll
  for (int r = 0; r < 2; ++r) {
    int v = t + r * 512;            // = s*256 + o
    int s = v >> 8, o = v & 255;
    float sum = 0.0f;
    for (int kb = 0; kb < 32; ++kb)
      sum += part[(size_t)kb * (1024 * 256) + (size_t)(sb + s) * 256 + o];
    cur3l[v] = sum + b1[o];
  }

  // ---- fc2 A-frags: A[m=lane&15][k=quad*8+jj], hi/lo exact split
  half8 a2h[8], a2l[8];
  {
    const float* wr = w2 + (size_t)(wave * 16 + n16) * 256 + quad * 8;
#pragma unroll
    for (int kt = 0; kt < 8; ++kt) {
      float4 u0 = *(const float4*)(wr + kt * 32);
      float4 u1 = *(const float4*)(wr + kt * 32 + 4);
      float wv[8] = {u0.x, u0.y, u0.z, u0.w, u1.x, u1.y, u1.z, u1.w};
#pragma unroll
      for (int e = 0; e < 8; ++e) {
        float hi = (float)(_Float16)wv[e];
        a2h[kt][e] = (_Float16)wv[e];
        a2l[kt][e] = (_Float16)(wv[e] - hi);
      }
    }
  }
  const float4 b2v = *(const float4*)(b2 + wave * 16 + quad * 4);
  float mem4[4] = {0.f, 0.f, 0.f, 0.f};

  // ---- fc3 A-frags (wave 0), rows >= 10 zero
  half8 a3h[4], a3l[4];
#pragma unroll
  for (int kt = 0; kt < 4; ++kt) { a3h[kt] = (half8){}; a3l[kt] = (half8){}; }
  if (n16 < 10) {
    const float* wr = w3 + (size_t)n16 * 128 + quad * 8;
#pragma unroll
    for (int kt = 0; kt < 4; ++kt) {
      float4 u0 = *(const float4*)(wr + kt * 32);
      float4 u1 = *(const float4*)(wr + kt * 32 + 4);
      float wv[8] = {u0.x, u0.y, u0.z, u0.w, u1.x, u1.y, u1.z, u1.w};
#pragma unroll
      for (int e = 0; e < 8; ++e) {
        float hi = (float)(_Float16)wv[e];
        a3h[kt][e] = (_Float16)wv[e];
        a3l[kt][e] = (_Float16)(wv[e] - hi);
      }
    }
  }
  float b3r[4];
#pragma unroll
  for (int r = 0; r < 4; ++r) {
    int cls = quad * 4 + r;
    b3r[r] = (cls < 10) ? b3[cls] : 0.0f;
  }
  float mem5[4] = {0.f, 0.f, 0.f, 0.f};

  __syncthreads();

  // ---- phase-1 state: threads 0..127, thread = (oct o = t>>2, sample s = t&3)
  float mem3[8], cur3r[8];
  if (t < 128) {
    const int o = t >> 2, s = t & 3;
    const float* cp = &cur3l[s * 256 + o * 8];
    float4 c0 = *(const float4*)cp;
    float4 c1 = *(const float4*)(cp + 4);
    cur3r[0] = c0.x; cur3r[1] = c0.y; cur3r[2] = c0.z; cur3r[3] = c0.w;
    cur3r[4] = c1.x; cur3r[5] = c1.y; cur3r[6] = c1.z; cur3r[7] = c1.w;
#pragma unroll
    for (int j = 0; j < 8; ++j) mem3[j] = 0.0f;
  }

  for (int step = 0; step < NSTEP; ++step) {
    // ---- fc3 for previous step (spk4[step-1] visible since barrier B)
    if (wave == 0 && step > 0) {
      float4v c0 = {0.f, 0.f, 0.f, 0.f}, c1 = {0.f, 0.f, 0.f, 0.f};
#pragma unroll
      for (int kt = 0; kt < 4; ++kt) {
        half8 b = *(const half8*)&spk4[(kt * 4 + quad) * 32 + n16 * 8];
        c0 = __builtin_amdgcn_mfma_f32_16x16x32_f16(a3h[kt], b, c0, 0, 0, 0);
        c1 = __builtin_amdgcn_mfma_f32_16x16x32_f16(a3l[kt], b, c1, 0, 0, 0);
      }
#pragma unroll
      for (int r = 0; r < 4; ++r) {
        int cls = quad * 4 + r;
        float cur5 = (c0[r] + c1[r]) + b3r[r];
        mem5[r] = lif_update(mem5[r], cur5);
        if (n16 < 4 && cls < 10)
          out[(size_t)(step - 1) * 10240 + (size_t)(sb + n16) * 10 + cls] =
              (mem5[r] > 1.0f) ? 1.0f : 0.0f;
      }
    }
    // ---- phase 1: mem3/spk3 (waves 0,1)
    if (t < 128) {
      const int o = t >> 2, s = t & 3;
      half8 sv;
#pragma unroll
      for (int j = 0; j < 8; ++j) {
        mem3[j] = lif_update(mem3[j], cur3r[j]);
        sv[j] = (_Float16)((mem3[j] > 1.0f) ? 1.0f : 0.0f);
      }
      *(half8*)&spk3[o * 32 + s * 8] = sv;
    }
    __syncthreads();   // A: spk3 visible; wave0 done reading spk4[step-1]
    {
      float4v acc0 = {0.f, 0.f, 0.f, 0.f}, acc1 = {0.f, 0.f, 0.f, 0.f};
#pragma unroll
      for (int kt = 0; kt < 8; ++kt) {
        half8 b = *(const half8*)&spk3[(kt * 4 + quad) * 32 + n16 * 8];
        acc0 = __builtin_amdgcn_mfma_f32_16x16x32_f16(a2h[kt], b, acc0, 0, 0, 0);
        acc1 = __builtin_amdgcn_mfma_f32_16x16x32_f16(a2l[kt], b, acc1, 0, 0, 0);
      }
      if (n16 < 4) {
        half4v pk;
#pragma unroll
        for (int r = 0; r < 4; ++r) {
          float cur4 = (acc0[r] + acc1[r]) + b2v[r];
          mem4[r] = lif_update(mem4[r], cur4);
          pk[r] = (_Float16)((mem4[r] > 1.0f) ? 1.0f : 0.0f);
        }
        *(half4v*)&spk4[(wave * 2 + (quad >> 1)) * 32 + n16 * 8 + (quad & 1) * 4] = pk;
      }
    }
    __syncthreads();   // B: spk4[step] visible
  }

  // ---- final fc3 (step NSTEP-1)
  if (wave == 0) {
    float4v c0 = {0.f, 0.f, 0.f, 0.f}, c1 = {0.f, 0.f, 0.f, 0.f};
#pragma unroll
    for (int kt = 0; kt < 4; ++kt) {
      half8 b = *(const half8*)&spk4[(kt * 4 + quad) * 32 + n16 * 8];
      c0 = __builtin_amdgcn_mfma_f32_16x16x32_f16(a3h[kt], b, c0, 0, 0, 0);
      c1 = __builtin_amdgcn_mfma_f32_16x16x32_f16(a3l[kt], b, c1, 0, 0, 0);
    }
#pragma unroll
    for (int r = 0; r < 4; ++r) {
      int cls = quad * 4 + r;
      float cur5 = (c0[r] + c1[r]) + b3r[r];
      mem5[r] = lif_update(mem5[r], cur5);
      if (n16 < 4 && cls < 10)
        out[(size_t)(NSTEP - 1) * 10240 + (size_t)(sb + n16) * 10 + cls] =
            (mem5[r] > 1.0f) ? 1.0f : 0.0f;
    }
  }
}

// ---------------------------------------------------------------- launcher
extern "C" void kernel_launch(void* const* d_in, const int* in_sizes, int n_in,
                              void* d_out, int out_size, void* d_ws, size_t ws_size,
                              hipStream_t stream) {
  (void)in_sizes; (void)n_in; (void)out_size; (void)ws_size;
  const float* x   = (const float*)d_in[0];
  const float* w1c = (const float*)d_in[1];
  const float* b1c = (const float*)d_in[2];
  const float* w2c = (const float*)d_in[3];
  const float* b2c = (const float*)d_in[4];
  const float* fw1 = (const float*)d_in[5];
  const float* fb1 = (const float*)d_in[6];
  const float* fw2 = (const float*)d_in[7];
  const float* fb2 = (const float*)d_in[8];
  const float* fw3 = (const float*)d_in[9];
  const float* fb3 = (const float*)d_in[10];
  float* out = (float*)d_out;

  char* ws = (char*)d_ws;
  float*    part  = (float*)ws;                       // 32 MB
  uint8_t*  c1q   = (uint8_t*)ws;                     // 16.8 MB, aliases part
  uint8_t*  xq    = (uint8_t*)(ws + (32u << 20));     //  8 MB
  _Float16* afrag = (_Float16*)(ws + (41u << 20));    // 72 KB
  _Float16* w1s   = (_Float16*)(ws + (42u << 20));    //  8 MB

  k_pc1<<<dim3(3144), dim3(256), 0, stream>>>(x, w1c, b1c, c1q, w2c, fw1, afrag, w1s);
  k_conv2<<<dim3(2048), dim3(256), 0, stream>>>(c1q, afrag, b2c, xq);
  k_fc1<<<dim3(512), dim3(256), 0, stream>>>(xq, w1s, part);
  k_lif<<<dim3(256), dim3(512), 0, stream>>>(part, fb1, fw2, fb2, fw3, fb3, out);
}